// Round 17
// baseline (125.897 us; speedup 1.0000x reference)
//
#include <hip/hip_runtime.h>
#include <hip/hip_fp16.h>
#include <math.h>

// FrFT (Ozaktas, 0.5<a<1.5): x[256,4096] f32, order f32 -> Re(complex64) f32
// out[b*4096+j]. R30: the occupancy experiment, THIRD attempt -- R15 died of
// launch-bounds spills, R16 died because grid=256 gives the scheduler no
// second block per CU regardless of resources.
//   s2_v8: grid 512 (j-split: 4 b-tiles x 128 j-tiles of 32), 1024 thr
//   (kq8 x fh2, one j-frag/wave, acc[4]). j-split keeps TOTAL cos work
//   unchanged (weights depend on (j,r) only). Per-block staging identical
//   (64 rows x 256-half chunks, proven gpos+rowXOR swizzle, po[2]);
//   LDS 64KB + VGPR ~48 -> 2 blocks/CU = 8 waves/SIMD: one block's
//   barrier stalls overlap the other's cos VALU.
//   Reduce: proven 4-round one-writer-per-plane, planes 64x32 (stride 36).
//   s1_v6 (Toeplitz keep-chain, CHW 512) and cvt_x untouched.
// Weight math proven through R13-R25; odd pad r=8191 weight-zeroed.

#define NN 4096
#define BB 256
#define KK (2*NN - 1)
#define CHW 512
#define CH2 256

typedef unsigned int uint;
typedef __attribute__((ext_vector_type(4))) float f32x4;
typedef __attribute__((ext_vector_type(2))) float f32x2;
typedef __attribute__((ext_vector_type(4))) uint u32x4;
typedef __attribute__((ext_vector_type(8))) _Float16 half8;
typedef __attribute__((ext_vector_type(4))) _Float16 half4;
typedef __attribute__((ext_vector_type(2))) __fp16 fp16x2;

struct LitConsts { float c, q, scale, pe; };

__device__ __forceinline__ LitConsts get_lit(const float* order) {
  float a = order[0];
  float alpha = a * (float)M_PI * 0.5f;
  float sina = sinf(alpha);
  float tana2 = tanf(alpha * 0.5f);
  LitConsts L;
  L.c = (float)M_PI / (float)NN / sina / 4.0f;
  L.q = ((float)M_PI / (float)NN) * (tana2 * 0.25f);
  L.scale = sqrtf(L.c / (float)M_PI);
  L.pe = -(1.0f - a) * (float)M_PI * 0.25f;
  return L;
}

__device__ __forceinline__ float xload(const float* __restrict__ x, uint idx, uint cap) {
  return (idx < cap) ? x[idx] : 0.f;
}

__device__ __forceinline__ uint pk2(float a, float b) {
  fp16x2 h = __builtin_amdgcn_cvt_pkrtz(a, b);
  return __builtin_bit_cast(uint, h);
}

__device__ __forceinline__ half8 pack8(const float* wv) {
  u32x4 u = { pk2(wv[0], wv[1]), pk2(wv[2], wv[3]),
              pk2(wv[4], wv[5]), pk2(wv[6], wv[7]) };
  return __builtin_bit_cast(half8, u);
}

// granule position permutation (16B granules within a row; bijective)
__device__ __forceinline__ int gpos(int s) { return s ^ (s >> 3); }

// sinc Toeplitz weight fragment: elements e=0..7 at t = t0 - e (R13-proven math)
__device__ __forceinline__ half8 mkw1(int t0) {
  const float C2PI = 0.63661977236758134f;
  float wv[8];
#pragma unroll
  for (int e = 0; e < 8; ++e) {
    const int t = t0 - e;
    const float sgn = (t & 1) ? -C2PI : C2PI;
    wv[e] = __fdividef(sgn, (float)(2 * t + 1));
  }
  return pack8(wv);
}

// ---- one-time x -> f16 (RTZ, same values R8 staged in LDS) ----
__global__ __launch_bounds__(256) void cvt_x(const float* __restrict__ x,
                                             _Float16* __restrict__ xh) {
  const int g = blockIdx.x * 256 + threadIdx.x;      // granule id (8 f32 each)
  const f32x4* p = (const f32x4*)(x + (size_t)g * 8);
  f32x4 a = p[0], b = p[1];
  u32x4 d = { pk2(a[0], a[1]), pk2(a[2], a[3]), pk2(b[0], b[1]), pk2(b[2], b[3]) };
  *(u32x4*)(xh + (size_t)g * 8) = d;
}

// ---- stage 1: sinc interp GEMM; 256 blocks x 1024 thr; tile 64b x 64s ----
// Wave frags at s-offsets {fh*16, fh*16+32}; frag_g1(st1) == frag_g0(st0).
__global__ __launch_bounds__(1024, 4) void s1_v6(const _Float16* __restrict__ xh,
                                                 _Float16* __restrict__ xiT) {
  __shared__ __align__(16) _Float16 U[2][64][CHW];   // 128 KB
  float* redf = (float*)&U[0][0][0];                 // aliased after k-loop
  const int tid = threadIdx.x;
  const int w = tid >> 6, lane = tid & 63;
  const int l15 = lane & 15, lhi = lane >> 4;
  const int kq = w & 7, fh = w >> 3;
  const int id = blockIdx.x, xcd = id & 7;
  const int b0 = (xcd >> 1) * 64;                    // same-b blocks -> XCD
  const int s0 = ((xcd & 1) | ((id >> 3) << 1)) * 64;
  const int srow = tid >> 4, t15 = tid & 15;
  const int swz = (srow & 7) << 4;

  const _Float16* xrow = xh + (size_t)(b0 + srow) * NN;

  f32x4 acc[4][2] = {};   // [fm][g]; g=0 -> s-off fh*16, g=1 -> fh*16+32
  u32x4 po[4];

  { // prologue: stage chunk 0
#pragma unroll
    for (int k = 0; k < 4; ++k)
      po[k] = *(const u32x4*)(xrow + (t15 + 16 * k) * 8);
    char* base = (char*)&U[0][srow][0];
#pragma unroll
    for (int k = 0; k < 4; ++k) {
      const int s = t15 + 16 * k;
      *(u32x4*)(base + ((gpos(s) << 4) ^ swz)) = po[k];
    }
  }

  for (int ch = 0; ch < 8; ++ch) {
    __syncthreads();
    const int cb = ch & 1;
    if (ch < 7) {
#pragma unroll
      for (int k = 0; k < 4; ++k)
        po[k] = *(const u32x4*)(xrow + (ch + 1) * CHW + (t15 + 16 * k) * 8);
    }
    const int i00 = ch * CHW + kq * 64 + lhi * 8;    // st = 0 k-base
    const int t00 = (s0 + fh * 16 + l15) - i00;      // g0 @ st0
    half8 keep;                                      // frag reused at st1/g1
    // ---- st = 0 ----
    {
      const int sg = kq * 8 + lhi;
      const int go = gpos(sg) << 4;
      half8 af[4];
#pragma unroll
      for (int fm = 0; fm < 4; ++fm) {
        const int row = fm * 16 + l15;
        af[fm] = *(const half8*)((const char*)&U[cb][row][0] + (go ^ ((row & 7) << 4)));
      }
      keep = mkw1(t00);                              // fresh g0
      const half8 bh1 = mkw1(t00 + 32);              // fresh g1
#pragma unroll
      for (int fm = 0; fm < 4; ++fm) {
        acc[fm][0] = __builtin_amdgcn_mfma_f32_16x16x32_f16(af[fm], keep, acc[fm][0], 0, 0, 0);
        acc[fm][1] = __builtin_amdgcn_mfma_f32_16x16x32_f16(af[fm], bh1, acc[fm][1], 0, 0, 0);
      }
    }
    // ---- st = 1 (i0 += 32): g1 reuses st0's g0 frag bit-identically ----
    {
      const int sg = kq * 8 + 4 + lhi;
      const int go = gpos(sg) << 4;
      half8 af[4];
#pragma unroll
      for (int fm = 0; fm < 4; ++fm) {
        const int row = fm * 16 + l15;
        af[fm] = *(const half8*)((const char*)&U[cb][row][0] + (go ^ ((row & 7) << 4)));
      }
      const half8 bh0 = mkw1(t00 - 32);              // fresh g0
#pragma unroll
      for (int fm = 0; fm < 4; ++fm) {
        acc[fm][0] = __builtin_amdgcn_mfma_f32_16x16x32_f16(af[fm], bh0, acc[fm][0], 0, 0, 0);
        acc[fm][1] = __builtin_amdgcn_mfma_f32_16x16x32_f16(af[fm], keep, acc[fm][1], 0, 0, 0);
      }
    }
    if (ch < 7) {
      char* base = (char*)&U[cb ^ 1][srow][0];
#pragma unroll
      for (int k = 0; k < 4; ++k) {
        const int s = t15 + 16 * k;
        *(u32x4*)(base + ((gpos(s) << 4) ^ swz)) = po[k];
      }
    }
  }

  // 8 kq-partials -> 4 red planes (aliased over U) in 2 rounds
  __syncthreads();
  if (kq < 4) {
#pragma unroll
    for (int fm = 0; fm < 4; ++fm)
#pragma unroll
      for (int g = 0; g < 2; ++g)
#pragma unroll
        for (int rr = 0; rr < 4; ++rr)
          redf[((kq * 64) + fm * 16 + lhi * 4 + rr) * 68 + fh * 16 + g * 32 + l15] =
              acc[fm][g][rr];
  }
  __syncthreads();
  if (kq >= 4) {
#pragma unroll
    for (int fm = 0; fm < 4; ++fm)
#pragma unroll
      for (int g = 0; g < 2; ++g)
#pragma unroll
        for (int rr = 0; rr < 4; ++rr)
          redf[(((kq - 4) * 64) + fm * 16 + lhi * 4 + rr) * 68 + fh * 16 + g * 32 + l15] +=
              acc[fm][g][rr];
  }
  __syncthreads();

  const int c0 = t15 * 4;
  half4 h;
#pragma unroll
  for (int e = 0; e < 4; ++e)
    h[e] = (_Float16)(redf[(srow) * 68 + c0 + e] + redf[(64 + srow) * 68 + c0 + e] +
                      redf[(128 + srow) * 68 + c0 + e] + redf[(192 + srow) * 68 + c0 + e]);
  *(half4*)(xiT + (size_t)(b0 + srow) * NN + s0 + c0) = h;
}

// ---- stage 2: fused even+odd chirp GEMM; 512 blocks (j-split), 2/CU ----
__global__ __launch_bounds__(1024, 4) void s2_v8(const _Float16* __restrict__ xh,
                                                 const _Float16* __restrict__ xiT,
                                                 const float* __restrict__ order,
                                                 float* __restrict__ out) {
  __shared__ __align__(16) _Float16 U[2][64][CH2];   // 64 KB
  float* redf = (float*)&U[0][0][0];
  const int tid = threadIdx.x;
  const int w = tid >> 6, lane = tid & 63;
  const int l15 = lane & 15, lhi = lane >> 4;
  const int kq = w & 7, fh = w >> 3;
  const int id = blockIdx.x, xcd = id & 7;
  const int b0 = (xcd >> 1) * 64;                    // 4 b-tiles (xcd pairs)
  const int j0 = ((xcd & 1) | ((id >> 3) << 1)) * 32;  // 128 j-tiles of 32
  const int srow = tid >> 4, t15 = tid & 15;
  const int swz = (srow & 7) << 4;

  const LitConsts L = get_lit(order);
  const float P2 = 4.f * (L.c - L.q);
  const int jl = j0 + fh * 16 + l15;
  const int nj = 2 * jl - (NN - 1);
  const float jbase = fmaf(-L.q, (float)(nj * nj), L.pe);

  const _Float16* xrow = xh + (size_t)(b0 + srow) * NN;
  const _Float16* orow = xiT + (size_t)(b0 + srow) * NN;

  f32x4 acc[4] = {};
  u32x4 po[2];

  { // prologue: stage even chunk 0
    po[0] = *(const u32x4*)(xrow + t15 * 8);
    po[1] = *(const u32x4*)(xrow + (t15 + 16) * 8);
    char* base = (char*)&U[0][srow][0];
    *(u32x4*)(base + ((gpos(t15) << 4) ^ swz)) = po[0];
    *(u32x4*)(base + ((gpos(t15 + 16) << 4) ^ swz)) = po[1];
  }

  // EVEN pass (r = 2i, A from xh); ch=15 prefetches odd chunk 0 from xiT
  for (int ch = 0; ch < 16; ++ch) {
    __syncthreads();
    const int cb = ch & 1;
    {
      const _Float16* src = (ch < 15) ? (xrow + (ch + 1) * CH2) : orow;
      po[0] = *(const u32x4*)(src + t15 * 8);
      po[1] = *(const u32x4*)(src + (t15 + 16) * 8);
    }
    {
      const int sg = kq * 4 + lhi;
      const int go = gpos(sg) << 4;
      half8 af[4];
#pragma unroll
      for (int fm = 0; fm < 4; ++fm) {
        const int row = fm * 16 + l15;
        af[fm] = *(const half8*)((const char*)&U[cb][row][0] + (go ^ ((row & 7) << 4)));
      }
      const int i0 = ch * CH2 + kq * 32 + lhi * 8;
      const int r0 = 2 * i0;
      const int k0 = r0 - (NN - 1);
      const float bk  = -L.q * (float)(k0 * k0);
      const float qk0 =  L.q * (float)k0;
      const int d0 = 2 * jl - r0;
      const float P0 = fmaf(L.c, (float)(d0 * d0), jbase + bk);
      const float P1 = -4.f * fmaf(L.c, (float)d0, qk0);
      float wv[8];
#pragma unroll
      for (int e = 0; e < 8; ++e) {
        const float ef = (float)e;
        wv[e] = __cosf(fmaf(ef, fmaf(ef, P2, P1), P0));
      }
      const half8 bh = pack8(wv);
#pragma unroll
      for (int fm = 0; fm < 4; ++fm)
        acc[fm] = __builtin_amdgcn_mfma_f32_16x16x32_f16(af[fm], bh, acc[fm], 0, 0, 0);
    }
    {
      char* base = (char*)&U[cb ^ 1][srow][0];
      *(u32x4*)(base + ((gpos(t15) << 4) ^ swz)) = po[0];
      *(u32x4*)(base + ((gpos(t15 + 16) << 4) ^ swz)) = po[1];
    }
  }

  // ODD pass (r = 2i+1, A from xiT); odd chunk 0 already in U[0]
  for (int ch = 0; ch < 16; ++ch) {
    __syncthreads();
    const int cb = ch & 1;
    if (ch < 15) {
      po[0] = *(const u32x4*)(orow + (ch + 1) * CH2 + t15 * 8);
      po[1] = *(const u32x4*)(orow + (ch + 1) * CH2 + (t15 + 16) * 8);
    }
    {
      const int sg = kq * 4 + lhi;
      const int go = gpos(sg) << 4;
      half8 af[4];
#pragma unroll
      for (int fm = 0; fm < 4; ++fm) {
        const int row = fm * 16 + l15;
        af[fm] = *(const half8*)((const char*)&U[cb][row][0] + (go ^ ((row & 7) << 4)));
      }
      const int i0 = ch * CH2 + kq * 32 + lhi * 8;
      const int r0 = 2 * i0 + 1;
      const int k0 = r0 - (NN - 1);
      const float bk  = -L.q * (float)(k0 * k0);
      const float qk0 =  L.q * (float)k0;
      const int d0 = 2 * jl - r0;
      const float P0 = fmaf(L.c, (float)(d0 * d0), jbase + bk);
      const float P1 = -4.f * fmaf(L.c, (float)d0, qk0);
      float wv[8];
#pragma unroll
      for (int e = 0; e < 8; ++e) {
        const float ef = (float)e;
        float t = __cosf(fmaf(ef, fmaf(ef, P2, P1), P0));
        if (i0 + e > NN - 2) t = 0.f;   // r=8191 pad does not exist
        wv[e] = t;
      }
      const half8 bh = pack8(wv);
#pragma unroll
      for (int fm = 0; fm < 4; ++fm)
        acc[fm] = __builtin_amdgcn_mfma_f32_16x16x32_f16(af[fm], bh, acc[fm], 0, 0, 0);
    }
    if (ch < 15) {
      char* base = (char*)&U[cb ^ 1][srow][0];
      *(u32x4*)(base + ((gpos(t15) << 4) ^ swz)) = po[0];
      *(u32x4*)(base + ((gpos(t15 + 16) << 4) ^ swz)) = po[1];
    }
  }

  // 8 kq-partials -> 2 planes (64x32, stride 36) in 4 ROUNDS + store
#pragma unroll
  for (int rnd = 0; rnd < 4; ++rnd) {
    __syncthreads();
    if ((kq >> 1) == rnd) {
      const int pl = kq & 1;
#pragma unroll
      for (int fm = 0; fm < 4; ++fm)
#pragma unroll
        for (int rr = 0; rr < 4; ++rr) {
          float* p = &redf[((pl * 64) + fm * 16 + lhi * 4 + rr) * 36 + fh * 16 + l15];
          if (rnd == 0) *p = acc[fm][rr];
          else          *p += acc[fm][rr];
        }
    }
  }
  __syncthreads();

  const int row = tid >> 4, c0 = (tid & 15) * 2;
  f32x2 v;
  v[0] = L.scale * (redf[row * 36 + c0]     + redf[(64 + row) * 36 + c0]);
  v[1] = L.scale * (redf[row * 36 + c0 + 1] + redf[(64 + row) * 36 + c0 + 1]);
  *(f32x2*)(out + (size_t)(b0 + row) * NN + j0 + c0) = v;
}

// ======================= R13 proven fallback (small ws) =======================

__global__ __launch_bounds__(256) void frft_interp(const float* __restrict__ x,
                                                   __half* __restrict__ xi,
                                                   int b_lo, int cnt,
                                                   uint xi_cap, uint x_cap) {
  __shared__ __align__(16) float wt1[32][64];
  __shared__ __align__(16) float xt[32][64];
  const int tid = threadIdx.x;
  const int s0 = blockIdx.x * 64, cb0 = blockIdx.y * 64;
  const int tx = tid & 15, ty = tid >> 4;
  const int ss0 = ty * 4, bb0 = tx * 4;

  float acc[4][4] = {};
  for (int i0 = 0; i0 < NN; i0 += 32) {
#pragma unroll
    for (int e = 0; e < 8; ++e) {
      int idx = tid + e * 256, qq = idx >> 6, ss = idx & 63;
      int t = s0 + ss - (i0 + qq);
      float sgn = (t & 1) ? -0.63661977236758134f : 0.63661977236758134f;
      wt1[qq][ss] = __fdividef(sgn, (float)(2 * t + 1));
    }
#pragma unroll
    for (int e = 0; e < 8; ++e) {
      int idx = tid + e * 256, qq = idx >> 6, bb = idx & 63;
      xt[qq][bb] = xload(x, (uint)(b_lo + cb0 + bb) * NN + (i0 + qq), x_cap);
    }
    __syncthreads();
#pragma unroll
    for (int qq = 0; qq < 32; ++qq) {
      float4 wv = *(const float4*)&wt1[qq][ss0];
      float4 uv = *(const float4*)&xt[qq][bb0];
      float w[4] = {wv.x, wv.y, wv.z, wv.w};
      float u[4] = {uv.x, uv.y, uv.z, uv.w};
#pragma unroll
      for (int aa = 0; aa < 4; ++aa)
#pragma unroll
        for (int cc = 0; cc < 4; ++cc) acc[aa][cc] = fmaf(w[aa], u[cc], acc[aa][cc]);
    }
    __syncthreads();
  }
#pragma unroll
  for (int aa = 0; aa < 4; ++aa) {
    int s = s0 + ss0 + aa;
    if (s < NN - 1) {
#pragma unroll
      for (int cc = 0; cc < 4; ++cc) {
        int cb = cb0 + bb0 + cc;
        if (cb < cnt) {
          uint o = (uint)s * (uint)cnt + (uint)cb;
          if (o < xi_cap) xi[o] = __float2half(acc[aa][cc]);
        }
      }
    }
  }
}

#define TJ 32
#define TB 64
#define TK 32
__global__ __launch_bounds__(256) void frft_gemm(const float* __restrict__ x,
                                                 const __half* __restrict__ xi,
                                                 const float* __restrict__ order,
                                                 float* __restrict__ out,
                                                 int b_lo, int cnt,
                                                 uint xi_cap, uint x_cap,
                                                 uint out_capf) {
  __shared__ __align__(16) float wt[TK][TJ];
  __shared__ __align__(16) float ut[TK][TB];
  const int tid = threadIdx.x;
  const int j0 = blockIdx.x * TJ, cb0 = blockIdx.y * TB;
  const int tx = tid & 15, ty = tid >> 4;
  const int jj0 = ty * 2, bb0 = tx * 4;

  LitConsts L = get_lit(order);
  float acc[2][4] = {};

  for (int r0 = 0; r0 < KK; r0 += TK) {
#pragma unroll
    for (int e = 0; e < 4; ++e) {
      int idx = tid + e * 256, qq = idx >> 5, jj = idx & 31;
      int r = r0 + qq;
      float wv = 0.f;
      if (r < KK) {
        int j = j0 + jj;
        int n = 2 * j - (NN - 1);
        int d = 2 * j - r;
        int k = r - (NN - 1);
        float base = fmaf(-L.q, (float)(n * n), L.pe);
        float ph = fmaf(L.c, (float)(d * d), fmaf(-L.q, (float)(k * k), base));
        wv = __cosf(ph);
      }
      wt[qq][jj] = wv;
    }
#pragma unroll
    for (int e = 0; e < 8; ++e) {
      int idx = tid + e * 256, qq = idx >> 6, bb = idx & 63;
      int r = r0 + qq, cb = cb0 + bb;
      float v = 0.f;
      if (r < KK && cb < cnt) {
        if (r & 1) {
          uint o = (uint)(r >> 1) * (uint)cnt + (uint)cb;
          v = (o < xi_cap) ? __half2float(xi[o]) : 0.f;
        } else {
          v = xload(x, (uint)(b_lo + cb) * NN + (uint)(r >> 1), x_cap);
        }
      }
      ut[qq][bb] = v;
    }
    __syncthreads();
#pragma unroll
    for (int qq = 0; qq < TK; ++qq) {
      float2 wv = *(const float2*)&wt[qq][jj0];
      float4 uv = *(const float4*)&ut[qq][bb0];
      float w[2] = {wv.x, wv.y};
      float u[4] = {uv.x, uv.y, uv.z, uv.w};
#pragma unroll
      for (int aa = 0; aa < 2; ++aa)
#pragma unroll
        for (int cc = 0; cc < 4; ++cc)
          acc[aa][cc] = fmaf(w[aa], u[cc], acc[aa][cc]);
    }
    __syncthreads();
  }

#pragma unroll
  for (int aa = 0; aa < 2; ++aa) {
    int j = j0 + jj0 + aa;
#pragma unroll
    for (int cc = 0; cc < 4; ++cc) {
      int cb = cb0 + bb0 + cc;
      if (cb < cnt) {
        uint idx = (uint)(b_lo + cb) * NN + (uint)j;
        if (idx < out_capf) out[idx] = L.scale * acc[aa][cc];
      }
    }
  }
}

__global__ __launch_bounds__(256) void frft_gemm1(const float* __restrict__ x,
                                                  const float* __restrict__ order,
                                                  float* __restrict__ out,
                                                  uint x_cap, uint out_capf) {
  __shared__ float xrow[NN];
  __shared__ float xio[NN - 1];
  __shared__ float red[4][64];
  const int tid = threadIdx.x;
  const int j0 = blockIdx.x * 64;
  LitConsts L = get_lit(order);

#pragma unroll
  for (int e = 0; e < 16; ++e) {
    int i = tid + e * 256;
    xrow[i] = xload(x, (uint)255 * NN + (uint)i, x_cap);
  }
  __syncthreads();
#pragma unroll
  for (int m = 0; m < 16; ++m) {
    int s = tid + m * 256;
    if (s < NN - 1) {
      float a0 = 0.f;
      for (int i = 0; i < NN; ++i) {
        int t = s - i;
        float sgn = (t & 1) ? -0.63661977236758134f : 0.63661977236758134f;
        a0 = fmaf(xrow[i], __fdividef(sgn, (float)(2 * t + 1)), a0);
      }
      xio[s] = a0;
    }
  }
  __syncthreads();

  const int ty = tid >> 6, jj = tid & 63;
  const int j = j0 + jj;
  const int n = 2 * j - (NN - 1);
  const float base = fmaf(-L.q, (float)(n * n), L.pe);
  float acc = 0.f;
  int rend = (ty + 1) * 2048; if (rend > KK) rend = KK;
  for (int r = ty * 2048; r < rend; ++r) {
    int d = 2 * j - r;
    int k = r - (NN - 1);
    float ph = fmaf(L.c, (float)(d * d), fmaf(-L.q, (float)(k * k), base));
    float u = (r & 1) ? xio[r >> 1] : xrow[r >> 1];
    acc = fmaf(__cosf(ph), u, acc);
  }
  red[ty][jj] = acc;
  __syncthreads();
  if (ty == 0) {
    float t = red[0][jj] + red[1][jj] + red[2][jj] + red[3][jj];
    uint idx = (uint)255 * NN + (uint)j;
    if (idx < out_capf) out[idx] = L.scale * t;
  }
}

extern "C" void kernel_launch(void* const* d_in, const int* in_sizes, int n_in,
                              void* d_out, int out_size, void* d_ws, size_t ws_size,
                              hipStream_t stream) {
  const float* x     = (const float*)d_in[0];
  const float* order = (const float*)d_in[1];
  float* outf = (float*)d_out;
  const uint x_cap    = (uint)in_sizes[0];
  const uint out_capf = (uint)out_size;
  const size_t ws_halves = ws_size / 2;

  const size_t XIT_H = (size_t)NN * BB;   // 1,048,576 halves (2 MB)

  // ---- R30 path: xiT (2 MB) + xh (2 MB) in ws; small dirty footprint ----
  if (ws_size >= XIT_H * 2 * 2 &&
      out_capf >= (uint)NN * BB && x_cap >= (uint)NN * BB) {
    _Float16* xiT = (_Float16*)d_ws;
    _Float16* xh  = xiT + XIT_H;
    cvt_x<<<dim3(512), 256, 0, stream>>>(x, xh);
    s1_v6<<<dim3(256), 1024, 0, stream>>>(xh, xiT);
    s2_v8<<<dim3(512), 1024, 0, stream>>>(xh, xiT, order, outf);
    return;
  }

  // ---- R13 proven fallback paths ----
  if (ws_halves >= (size_t)(NN - 1) * BB) {
    uint xi_cap = (uint)((size_t)(NN - 1) * BB);
    frft_interp<<<dim3(64, 4), 256, 0, stream>>>(x, (__half*)d_ws, 0, BB, xi_cap, x_cap);
    frft_gemm<<<dim3(NN / TJ, BB / TB), 256, 0, stream>>>(x, (__half*)d_ws, order, outf,
                                                          0, BB, xi_cap, x_cap, out_capf);
  } else {
    struct Chunk { int lo, cnt; };
    const Chunk ch[6] = { {0,170}, {170,57}, {227,19}, {246,6}, {252,2}, {254,1} };
    for (int i = 0; i < 6; ++i) {
      const Chunk& c = ch[i];
      uint off = (uint)(c.lo + c.cnt) * (uint)NN;
      __half* xp = (__half*)(outf + off);
      size_t need = (size_t)(NN - 1) * (size_t)c.cnt;
      size_t avail = (out_capf > off) ? (size_t)(out_capf - off) * 2 : 0;
      uint xi_cap = (uint)(need < avail ? need : avail);
      frft_interp<<<dim3(64, (unsigned)((c.cnt + 63) / 64)), 256, 0, stream>>>(
          x, xp, c.lo, c.cnt, xi_cap, x_cap);
      frft_gemm<<<dim3(NN / TJ, (unsigned)((c.cnt + TB - 1) / TB)), 256, 0, stream>>>(
          x, xp, order, outf, c.lo, c.cnt, xi_cap, x_cap, out_capf);
    }
    if (ws_halves >= (size_t)(NN - 1)) {
      uint xi_cap = (uint)(NN - 1);
      frft_interp<<<dim3(64, 1), 256, 0, stream>>>(x, (__half*)d_ws, 255, 1, xi_cap, x_cap);
      frft_gemm<<<dim3(NN / TJ, 1), 256, 0, stream>>>(x, (__half*)d_ws, order, outf,
                                                      255, 1, xi_cap, x_cap, out_capf);
    } else {
      frft_gemm1<<<64, 256, 0, stream>>>(x, order, outf, x_cap, out_capf);
    }
  }
}

// Round 18
// 115.418 us; speedup vs baseline: 1.0908x; 1.0908x over previous
//
#include <hip/hip_runtime.h>
#include <hip/hip_fp16.h>
#include <math.h>

// FrFT (Ozaktas, 0.5<a<1.5): x[256,4096] f32, order f32 -> Re(complex64) f32
// out[b*4096+j]. R31: revert to the best measured config (R12 = 115.2us).
//   Occupancy ledger R13-R17 (all regressions): reduce race / launch-bounds
//   spills / grid=256 no-second-block / j-split doubles per-CU staging+
//   barriers (54us). Conclusion: s2's ~40.7us is the VALU issue floor of
//   the 134M-cos weight stream, not latency exposure.
//   Config: cvt_x (one-time x->f16) + s1_v6 (Toeplitz keep-chain, CHW 512)
//   + s2_v5 (CHW 512, radian __cosf quadratic-phase weights).
//   Budget: fill 41.2 (harness re-poison, fixed) + s2 40.7 + s1 ~20 +
//   cvt/launch ~13 = ~115us.
// Weight math proven through R13-R25; odd pad r=8191 weight-zeroed.

#define NN 4096
#define BB 256
#define KK (2*NN - 1)
#define CHW 512

typedef unsigned int uint;
typedef __attribute__((ext_vector_type(4))) float f32x4;
typedef __attribute__((ext_vector_type(4))) uint u32x4;
typedef __attribute__((ext_vector_type(8))) _Float16 half8;
typedef __attribute__((ext_vector_type(4))) _Float16 half4;
typedef __attribute__((ext_vector_type(2))) __fp16 fp16x2;

struct LitConsts { float c, q, scale, pe; };

__device__ __forceinline__ LitConsts get_lit(const float* order) {
  float a = order[0];
  float alpha = a * (float)M_PI * 0.5f;
  float sina = sinf(alpha);
  float tana2 = tanf(alpha * 0.5f);
  LitConsts L;
  L.c = (float)M_PI / (float)NN / sina / 4.0f;
  L.q = ((float)M_PI / (float)NN) * (tana2 * 0.25f);
  L.scale = sqrtf(L.c / (float)M_PI);
  L.pe = -(1.0f - a) * (float)M_PI * 0.25f;
  return L;
}

__device__ __forceinline__ float xload(const float* __restrict__ x, uint idx, uint cap) {
  return (idx < cap) ? x[idx] : 0.f;
}

__device__ __forceinline__ uint pk2(float a, float b) {
  fp16x2 h = __builtin_amdgcn_cvt_pkrtz(a, b);
  return __builtin_bit_cast(uint, h);
}

__device__ __forceinline__ half8 pack8(const float* wv) {
  u32x4 u = { pk2(wv[0], wv[1]), pk2(wv[2], wv[3]),
              pk2(wv[4], wv[5]), pk2(wv[6], wv[7]) };
  return __builtin_bit_cast(half8, u);
}

// granule position permutation (16B granules within a 64-granule row)
__device__ __forceinline__ int gpos(int s) { return s ^ (s >> 3); }

// sinc Toeplitz weight fragment: elements e=0..7 at t = t0 - e (R13-proven math)
__device__ __forceinline__ half8 mkw1(int t0) {
  const float C2PI = 0.63661977236758134f;
  float wv[8];
#pragma unroll
  for (int e = 0; e < 8; ++e) {
    const int t = t0 - e;
    const float sgn = (t & 1) ? -C2PI : C2PI;
    wv[e] = __fdividef(sgn, (float)(2 * t + 1));
  }
  return pack8(wv);
}

// ---- one-time x -> f16 (RTZ, same values R8 staged in LDS) ----
__global__ __launch_bounds__(256) void cvt_x(const float* __restrict__ x,
                                             _Float16* __restrict__ xh) {
  const int g = blockIdx.x * 256 + threadIdx.x;      // granule id (8 f32 each)
  const f32x4* p = (const f32x4*)(x + (size_t)g * 8);
  f32x4 a = p[0], b = p[1];
  u32x4 d = { pk2(a[0], a[1]), pk2(a[2], a[3]), pk2(b[0], b[1]), pk2(b[2], b[3]) };
  *(u32x4*)(xh + (size_t)g * 8) = d;
}

// ---- stage 1: sinc interp GEMM; 256 blocks x 1024 thr; tile 64b x 64s ----
// Wave frags at s-offsets {fh*16, fh*16+32}; frag_g1(st1) == frag_g0(st0).
__global__ __launch_bounds__(1024, 4) void s1_v6(const _Float16* __restrict__ xh,
                                                 _Float16* __restrict__ xiT) {
  __shared__ __align__(16) _Float16 U[2][64][CHW];   // 128 KB
  float* redf = (float*)&U[0][0][0];                 // aliased after k-loop
  const int tid = threadIdx.x;
  const int w = tid >> 6, lane = tid & 63;
  const int l15 = lane & 15, lhi = lane >> 4;
  const int kq = w & 7, fh = w >> 3;
  const int id = blockIdx.x, xcd = id & 7;
  const int b0 = (xcd >> 1) * 64;                    // same-b blocks -> XCD
  const int s0 = ((xcd & 1) | ((id >> 3) << 1)) * 64;
  const int srow = tid >> 4, t15 = tid & 15;
  const int swz = (srow & 7) << 4;

  const _Float16* xrow = xh + (size_t)(b0 + srow) * NN;

  f32x4 acc[4][2] = {};   // [fm][g]; g=0 -> s-off fh*16, g=1 -> fh*16+32
  u32x4 po[4];

  { // prologue: stage chunk 0
#pragma unroll
    for (int k = 0; k < 4; ++k)
      po[k] = *(const u32x4*)(xrow + (t15 + 16 * k) * 8);
    char* base = (char*)&U[0][srow][0];
#pragma unroll
    for (int k = 0; k < 4; ++k) {
      const int s = t15 + 16 * k;
      *(u32x4*)(base + ((gpos(s) << 4) ^ swz)) = po[k];
    }
  }

  for (int ch = 0; ch < 8; ++ch) {
    __syncthreads();
    const int cb = ch & 1;
    if (ch < 7) {
#pragma unroll
      for (int k = 0; k < 4; ++k)
        po[k] = *(const u32x4*)(xrow + (ch + 1) * CHW + (t15 + 16 * k) * 8);
    }
    const int i00 = ch * CHW + kq * 64 + lhi * 8;    // st = 0 k-base
    const int t00 = (s0 + fh * 16 + l15) - i00;      // g0 @ st0
    half8 keep;                                      // frag reused at st1/g1
    // ---- st = 0 ----
    {
      const int sg = kq * 8 + lhi;
      const int go = gpos(sg) << 4;
      half8 af[4];
#pragma unroll
      for (int fm = 0; fm < 4; ++fm) {
        const int row = fm * 16 + l15;
        af[fm] = *(const half8*)((const char*)&U[cb][row][0] + (go ^ ((row & 7) << 4)));
      }
      keep = mkw1(t00);                              // fresh g0
      const half8 bh1 = mkw1(t00 + 32);              // fresh g1
#pragma unroll
      for (int fm = 0; fm < 4; ++fm) {
        acc[fm][0] = __builtin_amdgcn_mfma_f32_16x16x32_f16(af[fm], keep, acc[fm][0], 0, 0, 0);
        acc[fm][1] = __builtin_amdgcn_mfma_f32_16x16x32_f16(af[fm], bh1, acc[fm][1], 0, 0, 0);
      }
    }
    // ---- st = 1 (i0 += 32): g1 reuses st0's g0 frag bit-identically ----
    {
      const int sg = kq * 8 + 4 + lhi;
      const int go = gpos(sg) << 4;
      half8 af[4];
#pragma unroll
      for (int fm = 0; fm < 4; ++fm) {
        const int row = fm * 16 + l15;
        af[fm] = *(const half8*)((const char*)&U[cb][row][0] + (go ^ ((row & 7) << 4)));
      }
      const half8 bh0 = mkw1(t00 - 32);              // fresh g0
#pragma unroll
      for (int fm = 0; fm < 4; ++fm) {
        acc[fm][0] = __builtin_amdgcn_mfma_f32_16x16x32_f16(af[fm], bh0, acc[fm][0], 0, 0, 0);
        acc[fm][1] = __builtin_amdgcn_mfma_f32_16x16x32_f16(af[fm], keep, acc[fm][1], 0, 0, 0);
      }
    }
    if (ch < 7) {
      char* base = (char*)&U[cb ^ 1][srow][0];
#pragma unroll
      for (int k = 0; k < 4; ++k) {
        const int s = t15 + 16 * k;
        *(u32x4*)(base + ((gpos(s) << 4) ^ swz)) = po[k];
      }
    }
  }

  // 8 kq-partials -> 4 red planes (aliased over U) in 2 rounds
  __syncthreads();
  if (kq < 4) {
#pragma unroll
    for (int fm = 0; fm < 4; ++fm)
#pragma unroll
      for (int g = 0; g < 2; ++g)
#pragma unroll
        for (int rr = 0; rr < 4; ++rr)
          redf[((kq * 64) + fm * 16 + lhi * 4 + rr) * 68 + fh * 16 + g * 32 + l15] =
              acc[fm][g][rr];
  }
  __syncthreads();
  if (kq >= 4) {
#pragma unroll
    for (int fm = 0; fm < 4; ++fm)
#pragma unroll
      for (int g = 0; g < 2; ++g)
#pragma unroll
        for (int rr = 0; rr < 4; ++rr)
          redf[(((kq - 4) * 64) + fm * 16 + lhi * 4 + rr) * 68 + fh * 16 + g * 32 + l15] +=
              acc[fm][g][rr];
  }
  __syncthreads();

  const int c0 = t15 * 4;
  half4 h;
#pragma unroll
  for (int e = 0; e < 4; ++e)
    h[e] = (_Float16)(redf[(srow) * 68 + c0 + e] + redf[(64 + srow) * 68 + c0 + e] +
                      redf[(128 + srow) * 68 + c0 + e] + redf[(192 + srow) * 68 + c0 + e]);
  *(half4*)(xiT + (size_t)(b0 + srow) * NN + s0 + c0) = h;
}

// ---- stage 2: fused even+odd chirp GEMM; R10/R12-proven __cosf weights ----
__global__ __launch_bounds__(1024, 4) void s2_v5(const _Float16* __restrict__ xh,
                                                 const _Float16* __restrict__ xiT,
                                                 const float* __restrict__ order,
                                                 float* __restrict__ out) {
  __shared__ __align__(16) _Float16 U[2][64][CHW];
  float* redf = (float*)&U[0][0][0];
  const int tid = threadIdx.x;
  const int w = tid >> 6, lane = tid & 63;
  const int l15 = lane & 15, lhi = lane >> 4;
  const int kq = w & 7, fh = w >> 3;
  const int id = blockIdx.x, xcd = id & 7;
  const int b0 = (xcd >> 1) * 64;
  const int j0 = ((xcd & 1) | ((id >> 3) << 1)) * 64;
  const int srow = tid >> 4, t15 = tid & 15;
  const int swz = (srow & 7) << 4;

  const LitConsts L = get_lit(order);
  const float P2 = 4.f * (L.c - L.q);
  int jl[2]; float jbase[2];
#pragma unroll
  for (int g = 0; g < 2; ++g) {
    jl[g] = j0 + (fh * 2 + g) * 16 + l15;
    const int n = 2 * jl[g] - (NN - 1);
    jbase[g] = fmaf(-L.q, (float)(n * n), L.pe);
  }

  const _Float16* xrow = xh + (size_t)(b0 + srow) * NN;
  const _Float16* orow = xiT + (size_t)(b0 + srow) * NN;

  f32x4 acc[4][2] = {};
  u32x4 po[4];

  { // prologue: stage even chunk 0
#pragma unroll
    for (int k = 0; k < 4; ++k)
      po[k] = *(const u32x4*)(xrow + (t15 + 16 * k) * 8);
    char* base = (char*)&U[0][srow][0];
#pragma unroll
    for (int k = 0; k < 4; ++k) {
      const int s = t15 + 16 * k;
      *(u32x4*)(base + ((gpos(s) << 4) ^ swz)) = po[k];
    }
  }

  // EVEN pass (r = 2i, A from xh); ch=7 prefetches odd chunk 0 from xiT
  for (int ch = 0; ch < 8; ++ch) {
    __syncthreads();
    const int cb = ch & 1;
    {
      const _Float16* src = (ch < 7) ? (xrow + (ch + 1) * CHW) : orow;
#pragma unroll
      for (int k = 0; k < 4; ++k)
        po[k] = *(const u32x4*)(src + (t15 + 16 * k) * 8);
    }
#pragma unroll
    for (int st = 0; st < 2; ++st) {
      const int sg = kq * 8 + st * 4 + lhi;
      const int go = gpos(sg) << 4;
      half8 af[4];
#pragma unroll
      for (int fm = 0; fm < 4; ++fm) {
        const int row = fm * 16 + l15;
        af[fm] = *(const half8*)((const char*)&U[cb][row][0] + (go ^ ((row & 7) << 4)));
      }
      const int i0 = ch * CHW + kq * 64 + st * 32 + lhi * 8;
      const int r0 = 2 * i0;
      const int k0 = r0 - (NN - 1);
      const float bk  = -L.q * (float)(k0 * k0);
      const float qk0 =  L.q * (float)k0;
#pragma unroll
      for (int g = 0; g < 2; ++g) {
        const int d0 = 2 * jl[g] - r0;
        const float P0 = fmaf(L.c, (float)(d0 * d0), jbase[g] + bk);
        const float P1 = -4.f * fmaf(L.c, (float)d0, qk0);
        float wv[8];
#pragma unroll
        for (int e = 0; e < 8; ++e) {
          const float ef = (float)e;
          wv[e] = __cosf(fmaf(ef, fmaf(ef, P2, P1), P0));
        }
        const half8 bh = pack8(wv);
#pragma unroll
        for (int fm = 0; fm < 4; ++fm)
          acc[fm][g] = __builtin_amdgcn_mfma_f32_16x16x32_f16(af[fm], bh, acc[fm][g], 0, 0, 0);
      }
    }
    {
      char* base = (char*)&U[cb ^ 1][srow][0];
#pragma unroll
      for (int k = 0; k < 4; ++k) {
        const int s = t15 + 16 * k;
        *(u32x4*)(base + ((gpos(s) << 4) ^ swz)) = po[k];
      }
    }
  }

  // ODD pass (r = 2i+1, A from xiT); odd chunk 0 already in U[0]
  for (int ch = 0; ch < 8; ++ch) {
    __syncthreads();
    const int cb = ch & 1;
    if (ch < 7) {
#pragma unroll
      for (int k = 0; k < 4; ++k)
        po[k] = *(const u32x4*)(orow + (ch + 1) * CHW + (t15 + 16 * k) * 8);
    }
#pragma unroll
    for (int st = 0; st < 2; ++st) {
      const int sg = kq * 8 + st * 4 + lhi;
      const int go = gpos(sg) << 4;
      half8 af[4];
#pragma unroll
      for (int fm = 0; fm < 4; ++fm) {
        const int row = fm * 16 + l15;
        af[fm] = *(const half8*)((const char*)&U[cb][row][0] + (go ^ ((row & 7) << 4)));
      }
      const int i0 = ch * CHW + kq * 64 + st * 32 + lhi * 8;
      const int r0 = 2 * i0 + 1;
      const int k0 = r0 - (NN - 1);
      const float bk  = -L.q * (float)(k0 * k0);
      const float qk0 =  L.q * (float)k0;
#pragma unroll
      for (int g = 0; g < 2; ++g) {
        const int d0 = 2 * jl[g] - r0;
        const float P0 = fmaf(L.c, (float)(d0 * d0), jbase[g] + bk);
        const float P1 = -4.f * fmaf(L.c, (float)d0, qk0);
        float wv[8];
#pragma unroll
        for (int e = 0; e < 8; ++e) {
          const float ef = (float)e;
          float t = __cosf(fmaf(ef, fmaf(ef, P2, P1), P0));
          if (i0 + e > NN - 2) t = 0.f;   // r=8191 pad does not exist
          wv[e] = t;
        }
        const half8 bh = pack8(wv);
#pragma unroll
        for (int fm = 0; fm < 4; ++fm)
          acc[fm][g] = __builtin_amdgcn_mfma_f32_16x16x32_f16(af[fm], bh, acc[fm][g], 0, 0, 0);
      }
    }
    if (ch < 7) {
      char* base = (char*)&U[cb ^ 1][srow][0];
#pragma unroll
      for (int k = 0; k < 4; ++k) {
        const int s = t15 + 16 * k;
        *(u32x4*)(base + ((gpos(s) << 4) ^ swz)) = po[k];
      }
    }
  }

  // 8 kq-partials -> 4 red planes in 2 rounds + scaled store
  __syncthreads();
  if (kq < 4) {
#pragma unroll
    for (int fm = 0; fm < 4; ++fm)
#pragma unroll
      for (int g = 0; g < 2; ++g)
#pragma unroll
        for (int rr = 0; rr < 4; ++rr)
          redf[((kq * 64) + fm * 16 + lhi * 4 + rr) * 68 + (fh * 2 + g) * 16 + l15] =
              acc[fm][g][rr];
  }
  __syncthreads();
  if (kq >= 4) {
#pragma unroll
    for (int fm = 0; fm < 4; ++fm)
#pragma unroll
      for (int g = 0; g < 2; ++g)
#pragma unroll
        for (int rr = 0; rr < 4; ++rr)
          redf[(((kq - 4) * 64) + fm * 16 + lhi * 4 + rr) * 68 + (fh * 2 + g) * 16 + l15] +=
              acc[fm][g][rr];
  }
  __syncthreads();

  const int c0 = t15 * 4;
  f32x4 v;
#pragma unroll
  for (int e = 0; e < 4; ++e)
    v[e] = L.scale * (redf[(srow) * 68 + c0 + e] + redf[(64 + srow) * 68 + c0 + e] +
                      redf[(128 + srow) * 68 + c0 + e] + redf[(192 + srow) * 68 + c0 + e]);
  *(f32x4*)(out + (size_t)(b0 + srow) * NN + j0 + c0) = v;
}

// ======================= R13 proven fallback (small ws) =======================

__global__ __launch_bounds__(256) void frft_interp(const float* __restrict__ x,
                                                   __half* __restrict__ xi,
                                                   int b_lo, int cnt,
                                                   uint xi_cap, uint x_cap) {
  __shared__ __align__(16) float wt1[32][64];
  __shared__ __align__(16) float xt[32][64];
  const int tid = threadIdx.x;
  const int s0 = blockIdx.x * 64, cb0 = blockIdx.y * 64;
  const int tx = tid & 15, ty = tid >> 4;
  const int ss0 = ty * 4, bb0 = tx * 4;

  float acc[4][4] = {};
  for (int i0 = 0; i0 < NN; i0 += 32) {
#pragma unroll
    for (int e = 0; e < 8; ++e) {
      int idx = tid + e * 256, qq = idx >> 6, ss = idx & 63;
      int t = s0 + ss - (i0 + qq);
      float sgn = (t & 1) ? -0.63661977236758134f : 0.63661977236758134f;
      wt1[qq][ss] = __fdividef(sgn, (float)(2 * t + 1));
    }
#pragma unroll
    for (int e = 0; e < 8; ++e) {
      int idx = tid + e * 256, qq = idx >> 6, bb = idx & 63;
      xt[qq][bb] = xload(x, (uint)(b_lo + cb0 + bb) * NN + (i0 + qq), x_cap);
    }
    __syncthreads();
#pragma unroll
    for (int qq = 0; qq < 32; ++qq) {
      float4 wv = *(const float4*)&wt1[qq][ss0];
      float4 uv = *(const float4*)&xt[qq][bb0];
      float w[4] = {wv.x, wv.y, wv.z, wv.w};
      float u[4] = {uv.x, uv.y, uv.z, uv.w};
#pragma unroll
      for (int aa = 0; aa < 4; ++aa)
#pragma unroll
        for (int cc = 0; cc < 4; ++cc) acc[aa][cc] = fmaf(w[aa], u[cc], acc[aa][cc]);
    }
    __syncthreads();
  }
#pragma unroll
  for (int aa = 0; aa < 4; ++aa) {
    int s = s0 + ss0 + aa;
    if (s < NN - 1) {
#pragma unroll
      for (int cc = 0; cc < 4; ++cc) {
        int cb = cb0 + bb0 + cc;
        if (cb < cnt) {
          uint o = (uint)s * (uint)cnt + (uint)cb;
          if (o < xi_cap) xi[o] = __float2half(acc[aa][cc]);
        }
      }
    }
  }
}

#define TJ 32
#define TB 64
#define TK 32
__global__ __launch_bounds__(256) void frft_gemm(const float* __restrict__ x,
                                                 const __half* __restrict__ xi,
                                                 const float* __restrict__ order,
                                                 float* __restrict__ out,
                                                 int b_lo, int cnt,
                                                 uint xi_cap, uint x_cap,
                                                 uint out_capf) {
  __shared__ __align__(16) float wt[TK][TJ];
  __shared__ __align__(16) float ut[TK][TB];
  const int tid = threadIdx.x;
  const int j0 = blockIdx.x * TJ, cb0 = blockIdx.y * TB;
  const int tx = tid & 15, ty = tid >> 4;
  const int jj0 = ty * 2, bb0 = tx * 4;

  LitConsts L = get_lit(order);
  float acc[2][4] = {};

  for (int r0 = 0; r0 < KK; r0 += TK) {
#pragma unroll
    for (int e = 0; e < 4; ++e) {
      int idx = tid + e * 256, qq = idx >> 5, jj = idx & 31;
      int r = r0 + qq;
      float wv = 0.f;
      if (r < KK) {
        int j = j0 + jj;
        int n = 2 * j - (NN - 1);
        int d = 2 * j - r;
        int k = r - (NN - 1);
        float base = fmaf(-L.q, (float)(n * n), L.pe);
        float ph = fmaf(L.c, (float)(d * d), fmaf(-L.q, (float)(k * k), base));
        wv = __cosf(ph);
      }
      wt[qq][jj] = wv;
    }
#pragma unroll
    for (int e = 0; e < 8; ++e) {
      int idx = tid + e * 256, qq = idx >> 6, bb = idx & 63;
      int r = r0 + qq, cb = cb0 + bb;
      float v = 0.f;
      if (r < KK && cb < cnt) {
        if (r & 1) {
          uint o = (uint)(r >> 1) * (uint)cnt + (uint)cb;
          v = (o < xi_cap) ? __half2float(xi[o]) : 0.f;
        } else {
          v = xload(x, (uint)(b_lo + cb) * NN + (uint)(r >> 1), x_cap);
        }
      }
      ut[qq][bb] = v;
    }
    __syncthreads();
#pragma unroll
    for (int qq = 0; qq < TK; ++qq) {
      float2 wv = *(const float2*)&wt[qq][jj0];
      float4 uv = *(const float4*)&ut[qq][bb0];
      float w[2] = {wv.x, wv.y};
      float u[4] = {uv.x, uv.y, uv.z, uv.w};
#pragma unroll
      for (int aa = 0; aa < 2; ++aa)
#pragma unroll
        for (int cc = 0; cc < 4; ++cc)
          acc[aa][cc] = fmaf(w[aa], u[cc], acc[aa][cc]);
    }
    __syncthreads();
  }

#pragma unroll
  for (int aa = 0; aa < 2; ++aa) {
    int j = j0 + jj0 + aa;
#pragma unroll
    for (int cc = 0; cc < 4; ++cc) {
      int cb = cb0 + bb0 + cc;
      if (cb < cnt) {
        uint idx = (uint)(b_lo + cb) * NN + (uint)j;
        if (idx < out_capf) out[idx] = L.scale * acc[aa][cc];
      }
    }
  }
}

__global__ __launch_bounds__(256) void frft_gemm1(const float* __restrict__ x,
                                                  const float* __restrict__ order,
                                                  float* __restrict__ out,
                                                  uint x_cap, uint out_capf) {
  __shared__ float xrow[NN];
  __shared__ float xio[NN - 1];
  __shared__ float red[4][64];
  const int tid = threadIdx.x;
  const int j0 = blockIdx.x * 64;
  LitConsts L = get_lit(order);

#pragma unroll
  for (int e = 0; e < 16; ++e) {
    int i = tid + e * 256;
    xrow[i] = xload(x, (uint)255 * NN + (uint)i, x_cap);
  }
  __syncthreads();
#pragma unroll
  for (int m = 0; m < 16; ++m) {
    int s = tid + m * 256;
    if (s < NN - 1) {
      float a0 = 0.f;
      for (int i = 0; i < NN; ++i) {
        int t = s - i;
        float sgn = (t & 1) ? -0.63661977236758134f : 0.63661977236758134f;
        a0 = fmaf(xrow[i], __fdividef(sgn, (float)(2 * t + 1)), a0);
      }
      xio[s] = a0;
    }
  }
  __syncthreads();

  const int ty = tid >> 6, jj = tid & 63;
  const int j = j0 + jj;
  const int n = 2 * j - (NN - 1);
  const float base = fmaf(-L.q, (float)(n * n), L.pe);
  float acc = 0.f;
  int rend = (ty + 1) * 2048; if (rend > KK) rend = KK;
  for (int r = ty * 2048; r < rend; ++r) {
    int d = 2 * j - r;
    int k = r - (NN - 1);
    float ph = fmaf(L.c, (float)(d * d), fmaf(-L.q, (float)(k * k), base));
    float u = (r & 1) ? xio[r >> 1] : xrow[r >> 1];
    acc = fmaf(__cosf(ph), u, acc);
  }
  red[ty][jj] = acc;
  __syncthreads();
  if (ty == 0) {
    float t = red[0][jj] + red[1][jj] + red[2][jj] + red[3][jj];
    uint idx = (uint)255 * NN + (uint)j;
    if (idx < out_capf) out[idx] = L.scale * t;
  }
}

extern "C" void kernel_launch(void* const* d_in, const int* in_sizes, int n_in,
                              void* d_out, int out_size, void* d_ws, size_t ws_size,
                              hipStream_t stream) {
  const float* x     = (const float*)d_in[0];
  const float* order = (const float*)d_in[1];
  float* outf = (float*)d_out;
  const uint x_cap    = (uint)in_sizes[0];
  const uint out_capf = (uint)out_size;
  const size_t ws_halves = ws_size / 2;

  const size_t XIT_H = (size_t)NN * BB;   // 1,048,576 halves (2 MB)

  // ---- R31 path: xiT (2 MB) + xh (2 MB) in ws; small dirty footprint ----
  if (ws_size >= XIT_H * 2 * 2 &&
      out_capf >= (uint)NN * BB && x_cap >= (uint)NN * BB) {
    _Float16* xiT = (_Float16*)d_ws;
    _Float16* xh  = xiT + XIT_H;
    cvt_x<<<dim3(512), 256, 0, stream>>>(x, xh);
    s1_v6<<<dim3(256), 1024, 0, stream>>>(xh, xiT);
    s2_v5<<<dim3(256), 1024, 0, stream>>>(xh, xiT, order, outf);
    return;
  }

  // ---- R13 proven fallback paths ----
  if (ws_halves >= (size_t)(NN - 1) * BB) {
    uint xi_cap = (uint)((size_t)(NN - 1) * BB);
    frft_interp<<<dim3(64, 4), 256, 0, stream>>>(x, (__half*)d_ws, 0, BB, xi_cap, x_cap);
    frft_gemm<<<dim3(NN / TJ, BB / TB), 256, 0, stream>>>(x, (__half*)d_ws, order, outf,
                                                          0, BB, xi_cap, x_cap, out_capf);
  } else {
    struct Chunk { int lo, cnt; };
    const Chunk ch[6] = { {0,170}, {170,57}, {227,19}, {246,6}, {252,2}, {254,1} };
    for (int i = 0; i < 6; ++i) {
      const Chunk& c = ch[i];
      uint off = (uint)(c.lo + c.cnt) * (uint)NN;
      __half* xp = (__half*)(outf + off);
      size_t need = (size_t)(NN - 1) * (size_t)c.cnt;
      size_t avail = (out_capf > off) ? (size_t)(out_capf - off) * 2 : 0;
      uint xi_cap = (uint)(need < avail ? need : avail);
      frft_interp<<<dim3(64, (unsigned)((c.cnt + 63) / 64)), 256, 0, stream>>>(
          x, xp, c.lo, c.cnt, xi_cap, x_cap);
      frft_gemm<<<dim3(NN / TJ, (unsigned)((c.cnt + TB - 1) / TB)), 256, 0, stream>>>(
          x, xp, order, outf, c.lo, c.cnt, xi_cap, x_cap, out_capf);
    }
    if (ws_halves >= (size_t)(NN - 1)) {
      uint xi_cap = (uint)(NN - 1);
      frft_interp<<<dim3(64, 1), 256, 0, stream>>>(x, (__half*)d_ws, 255, 1, xi_cap, x_cap);
      frft_gemm<<<dim3(NN / TJ, 1), 256, 0, stream>>>(x, (__half*)d_ws, order, outf,
                                                      255, 1, xi_cap, x_cap, out_capf);
    } else {
      frft_gemm1<<<64, 256, 0, stream>>>(x, order, outf, x_cap, out_capf);
    }
  }
}